// Round 7
// baseline (370.368 us; speedup 1.0000x reference)
//
#include <hip/hip_runtime.h>

// CostVolume v9 — v8's 9-wave geometry + sched_barrier-pinned channel pipeline.
//
// v8 post-mortem: geometry is right (FETCH 558->160MB, all 9 waves share in2
// on-CU; occupancy 57%) but the allocator granted 32 VGPRs vs ~50 demand
// (acc28+w4 = exactly 32, zero room for the 12-float window) -> the 4 loads
// per channel-iter serialized into ~4x140cyc round trips (216us = ~570
// cyc/iter, VALU 19%, HBM 18%). Fourth allocator fight: the scheduler reduces
// pressure toward the 8-wave/32-reg tier even though 3 blocks/CU (27 waves)
// only needs <=75 regs.
//
// v9 levers (geometry unchanged):
//  1) x2-unrolled channel loop: issue c+1's 4 loads, then
//     __builtin_amdgcn_sched_barrier(0), then c's FMAs. Sinking the loads past
//     the compute becomes ILLEGAL -> 4 loads stay in flight under ~70cyc of
//     FMAs, consumed via counted vmcnt next half-iter.
//  2) amdgpu_waves_per_eu(6,7): pressure target 6-7 waves/EU = 73-85 regs
//     (not 8 waves = 32-64). Demand ~72 (28 acc + 24 dbuf window + 8 w + addr)
//     -> no spill (cap 85), residency still 3 blocks/CU.
//
// out[n,d,y,x] = (1/64) * sum_c in1_pad[n,c, y+dy_d-4, x+dx_d-4] * in2[n,c,y,x]
// Block = 576 thr = 9 waves, wave w == window row dy=w, same 64 pixel-quads.
// One thread owns 4 consecutive x. Window row = 12 floats = 3 aligned float4
// loads shared by 4 pixels and all dx of the row. No guards in the hot loop:
// row index clamped to [0,159], first/last loads clamped into the buffer;
// garbage lands only in acc slots whose TRUE source index is OOB, zeroed in
// the epilogue (OOB-ness of a (d,pixel) is uniform across channels == the
// reference's zero padding). XCD swizzle: 200 contiguous blocks = one n image
// per XCD.

#define HH 160
#define WW 320
#define CHN 64
#define ND 53
#define HW4 (HH * WW * 4)      /* 204800 bytes per (n,c) plane */
#define ROW4 (WW * 4)          /* 1280 bytes per row */
#define IMG4 (CHN * HW4)       /* 13107200 bytes per n image */
#define SIZEB (8 * IMG4)       /* 104857600 bytes total in1 */
#define OIMG4 (ND * HW4)       /* out bytes per n */

__global__
__attribute__((amdgpu_flat_work_group_size(576, 576), amdgpu_waves_per_eu(6, 7)))
void cost_volume_9wp(const float* __restrict__ in1,
                     const float* __restrict__ in2,
                     float* __restrict__ out) {
    const int wv   = threadIdx.x >> 6;        // 0..8 == dy
    const int lane = threadIdx.x & 63;
    const int bid  = blockIdx.x;              // 0..1599
    const int sb   = (bid & 7) * 200 + (bid >> 3);   // XCD swizzle, bijective
    const int q    = sb * 64 + lane;          // pixel-quad id, 0..102399

    const int xg = q % 80;
    const int x0 = xg * 4;
    const int y  = (q / 80) % HH;
    const int n  = q / (80 * HH);

    const char* p1 = (const char*)in1;
    const char* p2 = (const char*)in2;

    // this wave's window row (clamped; OOB handled in epilogue)
    const int yy0 = y + wv - 4;
    const int yc  = yy0 < 0 ? 0 : (yy0 > HH - 1 ? HH - 1 : yy0);
    const int r0  = yc * ROW4;
    const bool ry = (yy0 >= 0) && (yy0 < HH);

    int pc = n * IMG4 + x0 * 4 - 16;          // in1 byte base (c0, row0, x0-4)
    int i2 = n * IMG4 + (y * WW + x0) * 4;    // in2 byte offset (c0)

    // Load one channel's data: in2 quad + this wave's 12-float window row
    // (3 float4, ends clamped into the buffer; off >= -16 so mid load >= 0,
    // max end exactly SIZEB).
    #define LDR(FS, WS, PC, I2) { \
        WS = *(const float4*)(p2 + (I2)); \
        const int off = (PC) + r0; \
        const int oa = off < 0 ? 0 : off; \
        const int oc = (off + 32 > SIZEB - 16) ? (SIZEB - 16) : (off + 32); \
        const float4 va = *(const float4*)(p1 + oa); \
        const float4 vb = *(const float4*)(p1 + off + 16); \
        const float4 vc = *(const float4*)(p1 + oc); \
        FS[0]=va.x; FS[1]=va.y; FS[2]=va.z;  FS[3]=va.w; \
        FS[4]=vb.x; FS[5]=vb.y; FS[6]=vb.z;  FS[7]=vb.w; \
        FS[8]=vc.x; FS[9]=vc.y; FS[10]=vc.z; FS[11]=vc.w; }

    // acc[A] pixel px += FS[J+px] * WS[px]   (J = dx)
    #define AC(A, J, FS, WS) \
        acc[A].x = fmaf(FS[(J)+0], WS.x, acc[A].x); \
        acc[A].y = fmaf(FS[(J)+1], WS.y, acc[A].y); \
        acc[A].z = fmaf(FS[(J)+2], WS.z, acc[A].z); \
        acc[A].w = fmaf(FS[(J)+3], WS.w, acc[A].w);

    // Double-buffered, sched_barrier-pinned channel pipeline.
    // Loads for the NEXT channel issue, then the barrier forbids sinking them
    // past the CURRENT channel's FMAs.
    #define CHPIPE(CMPM) \
        LDR(fA, wA, pc, i2) \
        _Pragma("unroll 1") \
        for (int c = 0; c < CHN - 2; c += 2) { \
            LDR(fB, wB, pc + HW4, i2 + HW4) \
            __builtin_amdgcn_sched_barrier(0); \
            CMPM(fA, wA) \
            pc += 2 * HW4; i2 += 2 * HW4; \
            LDR(fA, wA, pc, i2) \
            __builtin_amdgcn_sched_barrier(0); \
            CMPM(fB, wB) \
        } \
        LDR(fB, wB, pc + HW4, i2 + HW4) \
        __builtin_amdgcn_sched_barrier(0); \
        CMPM(fA, wA) \
        CMPM(fB, wB)

    const float s = 1.0f / 64.0f;
    char* po = (char*)out + (size_t)n * OIMG4 + (size_t)((y * WW + x0) * 4);
    bool xok[12];
    #pragma unroll
    for (int j = 0; j < 12; ++j) { const int xx = x0 + j - 4; xok[j] = (xx >= 0) && (xx < WW); }

    #define EPI(A, D, DX) { \
        float4 rr; \
        rr.x = (ry && xok[(DX)+0]) ? acc[A].x * s : 0.f; \
        rr.y = (ry && xok[(DX)+1]) ? acc[A].y * s : 0.f; \
        rr.z = (ry && xok[(DX)+2]) ? acc[A].z * s : 0.f; \
        rr.w = (ry && xok[(DX)+3]) ? acc[A].w * s : 0.f; \
        *(float4*)(po + (size_t)(D) * HW4) = rr; }

    switch (wv) {
    case 0: { // dy0: dx{0,2,4,6,8} -> d0..4
        float4 acc[5] = {}; float fA[12], fB[12]; float4 wA, wB;
        #define CMP0(FS, WS) AC(0,0,FS,WS) AC(1,2,FS,WS) AC(2,4,FS,WS) AC(3,6,FS,WS) AC(4,8,FS,WS)
        CHPIPE(CMP0)
        EPI(0,0,0) EPI(1,1,2) EPI(2,2,4) EPI(3,3,6) EPI(4,4,8)
        break; }
    case 1: { // dy1: dx{1,3,5,7} -> d5..8
        float4 acc[4] = {}; float fA[12], fB[12]; float4 wA, wB;
        #define CMP1(FS, WS) AC(0,1,FS,WS) AC(1,3,FS,WS) AC(2,5,FS,WS) AC(3,7,FS,WS)
        CHPIPE(CMP1)
        EPI(0,5,1) EPI(1,6,3) EPI(2,7,5) EPI(3,8,7)
        break; }
    case 2: { // dy2: dx{0,2,3,4,5,6,8} -> d9..15
        float4 acc[7] = {}; float fA[12], fB[12]; float4 wA, wB;
        #define CMP2(FS, WS) AC(0,0,FS,WS) AC(1,2,FS,WS) AC(2,3,FS,WS) AC(3,4,FS,WS) AC(4,5,FS,WS) AC(5,6,FS,WS) AC(6,8,FS,WS)
        CHPIPE(CMP2)
        EPI(0,9,0) EPI(1,10,2) EPI(2,11,3) EPI(3,12,4) EPI(4,13,5) EPI(5,14,6) EPI(6,15,8)
        break; }
    case 3: { // dy3: dx{1..7} -> d16..22
        float4 acc[7] = {}; float fA[12], fB[12]; float4 wA, wB;
        #define CMP3(FS, WS) AC(0,1,FS,WS) AC(1,2,FS,WS) AC(2,3,FS,WS) AC(3,4,FS,WS) AC(4,5,FS,WS) AC(5,6,FS,WS) AC(6,7,FS,WS)
        CHPIPE(CMP3)
        EPI(0,16,1) EPI(1,17,2) EPI(2,18,3) EPI(3,19,4) EPI(4,20,5) EPI(5,21,6) EPI(6,22,7)
        break; }
    case 4: { // dy4: dx{0,2,3,4,5,6,8} -> d23..29
        float4 acc[7] = {}; float fA[12], fB[12]; float4 wA, wB;
        #define CMP4(FS, WS) AC(0,0,FS,WS) AC(1,2,FS,WS) AC(2,3,FS,WS) AC(3,4,FS,WS) AC(4,5,FS,WS) AC(5,6,FS,WS) AC(6,8,FS,WS)
        CHPIPE(CMP4)
        EPI(0,23,0) EPI(1,24,2) EPI(2,25,3) EPI(3,26,4) EPI(4,27,5) EPI(5,28,6) EPI(6,29,8)
        break; }
    case 5: { // dy5: dx{1..7} -> d30..36
        float4 acc[7] = {}; float fA[12], fB[12]; float4 wA, wB;
        #define CMP5(FS, WS) AC(0,1,FS,WS) AC(1,2,FS,WS) AC(2,3,FS,WS) AC(3,4,FS,WS) AC(4,5,FS,WS) AC(5,6,FS,WS) AC(6,7,FS,WS)
        CHPIPE(CMP5)
        EPI(0,30,1) EPI(1,31,2) EPI(2,32,3) EPI(3,33,4) EPI(4,34,5) EPI(5,35,6) EPI(6,36,7)
        break; }
    case 6: { // dy6: dx{0,2,3,4,5,6,8} -> d37..43
        float4 acc[7] = {}; float fA[12], fB[12]; float4 wA, wB;
        #define CMP6(FS, WS) AC(0,0,FS,WS) AC(1,2,FS,WS) AC(2,3,FS,WS) AC(3,4,FS,WS) AC(4,5,FS,WS) AC(5,6,FS,WS) AC(6,8,FS,WS)
        CHPIPE(CMP6)
        EPI(0,37,0) EPI(1,38,2) EPI(2,39,3) EPI(3,40,4) EPI(4,41,5) EPI(5,42,6) EPI(6,43,8)
        break; }
    case 7: { // dy7: dx{1,3,5,7} -> d44..47
        float4 acc[4] = {}; float fA[12], fB[12]; float4 wA, wB;
        #define CMP7(FS, WS) AC(0,1,FS,WS) AC(1,3,FS,WS) AC(2,5,FS,WS) AC(3,7,FS,WS)
        CHPIPE(CMP7)
        EPI(0,44,1) EPI(1,45,3) EPI(2,46,5) EPI(3,47,7)
        break; }
    default: { // dy8: dx{0,2,4,6,8} -> d48..52
        float4 acc[5] = {}; float fA[12], fB[12]; float4 wA, wB;
        #define CMP8(FS, WS) AC(0,0,FS,WS) AC(1,2,FS,WS) AC(2,4,FS,WS) AC(3,6,FS,WS) AC(4,8,FS,WS)
        CHPIPE(CMP8)
        EPI(0,48,0) EPI(1,49,2) EPI(2,50,4) EPI(3,51,6) EPI(4,52,8)
        break; }
    }
    #undef LDR
    #undef AC
    #undef CHPIPE
    #undef EPI
}

extern "C" void kernel_launch(void* const* d_in, const int* in_sizes, int n_in,
                              void* d_out, int out_size, void* d_ws, size_t ws_size,
                              hipStream_t stream) {
    const float* in1 = (const float*)d_in[0];
    const float* in2 = (const float*)d_in[1];
    float* out = (float*)d_out;

    // 1600 blocks x 576 threads (9 waves, one per dy row; 64 pixel-quads/block)
    dim3 grid(1600);
    dim3 block(576);
    cost_volume_9wp<<<grid, block, 0, stream>>>(in1, in2, out);
}